// Round 2
// baseline (621.534 us; speedup 1.0000x reference)
//
#include <hip/hip_runtime.h>

// ---------------------------------------------------------------------------
// Bengio03HighwayBiLm: L=2 layers of {windowed conv GEMM + 2 highway steps},
// fwd+bwd directions. fp16 MFMA (16x16x32), fp32 accum.
// B=32 S=512 H=512 W=3 IN=2048 NHW=2
// ---------------------------------------------------------------------------

typedef __attribute__((ext_vector_type(8))) _Float16 h8;
typedef __attribute__((ext_vector_type(4))) float f4;

#define AS1(p) ((__attribute__((address_space(1))) void*)(p))
#define AS3(p) ((__attribute__((address_space(3))) void*)(p))

// ---- fp32 -> fp16 conversion (vector x4) ----------------------------------
__global__ void cvt_kernel(const float* __restrict__ in, _Float16* __restrict__ out, int n) {
  int i = (blockIdx.x * blockDim.x + threadIdx.x) * 4;
  if (i >= n) return;
  float4 v = *reinterpret_cast<const float4*>(in + i);
  union { _Float16 h[4]; unsigned long long u; } p;
  p.h[0] = (_Float16)v.x; p.h[1] = (_Float16)v.y;
  p.h[2] = (_Float16)v.z; p.h[3] = (_Float16)v.w;
  *reinterpret_cast<unsigned long long*>(out + i) = p.u;
}

// ---------------------------------------------------------------------------
// Conv GEMM: C[m,h] = relu( sum_{k<2048} win[m,k] * W[h,k] + bias[h] )
// win[m=b*512+s, k] = padded[b, s*512 + k] (fwd) / padded[b, (s+3)*512 + k] (bwd)
// padded rows t: t<3 -> fwd_pad[t], 3<=t<515 -> x[t-3], t>=515 -> bwd_pad[t-515]
// Tile 128x128, BK=64, 4 waves (2x2), each wave 64x64 (4x4 frags 16x16).
// LDS XOR-swizzle: byte ^= ((row&7)<<4), applied on SOURCE addr at staging
// (global_load_lds writes linearly) and on ds_read addr.
// ---------------------------------------------------------------------------
__global__ __launch_bounds__(256, 2) void conv_kernel(
    const _Float16* __restrict__ xinF, const _Float16* __restrict__ xinB,
    const _Float16* __restrict__ wF,   const _Float16* __restrict__ wB,
    const float* __restrict__ biasF,   const float* __restrict__ biasB,
    const _Float16* __restrict__ padF, const _Float16* __restrict__ padB,
    _Float16* __restrict__ xoutF,      _Float16* __restrict__ xoutB)
{
  const int dir = blockIdx.z;
  const _Float16* xin  = dir ? xinB  : xinF;
  const _Float16* wgt  = dir ? wB    : wF;
  const float*    bias = dir ? biasB : biasF;
  _Float16*       xout = dir ? xoutB : xoutF;
  const int tof = dir ? 3 : 0;

  const int n0 = blockIdx.x << 7;
  const int m0 = blockIdx.y << 7;
  const int b  = m0 >> 9;
  const int s0 = m0 & 511;

  __shared__ char smem[32768];
  char* smA = smem;
  char* smB = smem + 16384;

  const int tid  = threadIdx.x;
  const int lane = tid & 63;
  const int wv   = tid >> 6;
  const int wm   = wv >> 1, wn = wv & 1;
  const int r15  = lane & 15, rk = lane >> 4;
  const int swz  = (r15 & 7) << 4;

  f4 acc[4][4] = {};

  for (int kt = 0; kt < 32; ++kt) {
    const int kbase = kt << 6;
    __syncthreads();
    // stage A tile [128 rows][64 k] (16 KB), 4 chunks of 16B per thread
    #pragma unroll
    for (int i = 0; i < 4; ++i) {
      const int c   = (i << 8) + tid;           // chunk index 0..1023
      const int row = c >> 3;                   // 0..127
      const int cbs = ((c & 7) << 4) ^ ((row & 7) << 4);  // swizzled src byte col
      const int kg  = kbase + (cbs >> 1);       // global k element index
      const int t   = s0 + row + tof + (kg >> 9);
      const int hh  = kg & 511;
      const _Float16* src;
      if (t < 3)        src = padF + t * 512 + hh;
      else if (t < 515) src = xin + ((((size_t)(b << 9)) + (t - 3)) << 9) + hh;
      else              src = padB + (t - 515) * 512 + hh;
      char* dst = smA + (((i << 8) + (tid & 192)) << 4);  // wave-uniform base
      __builtin_amdgcn_global_load_lds(AS1(src), AS3(dst), 16, 0, 0);
    }
    // stage B tile: W[h=n0+row][k]
    #pragma unroll
    for (int i = 0; i < 4; ++i) {
      const int c   = (i << 8) + tid;
      const int row = c >> 3;
      const int cbs = ((c & 7) << 4) ^ ((row & 7) << 4);
      const _Float16* src = wgt + (((size_t)(n0 + row)) << 11) + kbase + (cbs >> 1);
      char* dst = smB + (((i << 8) + (tid & 192)) << 4);
      __builtin_amdgcn_global_load_lds(AS1(src), AS3(dst), 16, 0, 0);
    }
    asm volatile("s_waitcnt vmcnt(0)" ::: "memory");
    __syncthreads();
    // compute: 2 k-halves x 16 MFMA
    #pragma unroll
    for (int kk = 0; kk < 2; ++kk) {
      h8 av[4], bv[4];
      #pragma unroll
      for (int mi = 0; mi < 4; ++mi) {
        const int row = (wm << 6) + (mi << 4) + r15;
        av[mi] = *reinterpret_cast<const h8*>(smA + row * 128 + (((kk << 6) + (rk << 4)) ^ swz));
      }
      #pragma unroll
      for (int ni = 0; ni < 4; ++ni) {
        const int row = (wn << 6) + (ni << 4) + r15;
        bv[ni] = *reinterpret_cast<const h8*>(smB + row * 128 + (((kk << 6) + (rk << 4)) ^ swz));
      }
      #pragma unroll
      for (int mi = 0; mi < 4; ++mi)
        #pragma unroll
        for (int ni = 0; ni < 4; ++ni)
          acc[mi][ni] = __builtin_amdgcn_mfma_f32_16x16x32_f16(av[mi], bv[ni], acc[mi][ni], 0, 0, 0);
    }
  }

  // epilogue: +bias, relu, store fp16
  #pragma unroll
  for (int ni = 0; ni < 4; ++ni) {
    const int col = n0 + (wn << 6) + (ni << 4) + r15;
    const float bb = bias[col];
    #pragma unroll
    for (int mi = 0; mi < 4; ++mi) {
      const int mr = m0 + (wm << 6) + (mi << 4) + (rk << 2);
      #pragma unroll
      for (int r = 0; r < 4; ++r) {
        float v = acc[mi][ni][r] + bb;
        v = fmaxf(v, 0.f);
        xout[(((size_t)(mr + r)) << 9) + col] = (_Float16)v;
      }
    }
  }
}

// ---------------------------------------------------------------------------
// Highway step: proj[m,g] = sum_h x[m,h]*hw_w[g,h]+hw_b[g], g in [0,1024)
// x_new = sig(proj[512+h])*x + (1-sig)*relu(proj[h])
// Each block: A tile 128x64 + TWO B tiles (nonlin rows n0.., gate rows 512+n0..)
// ---------------------------------------------------------------------------
__global__ __launch_bounds__(256, 2) void hw_kernel(
    const _Float16* __restrict__ xinF, const _Float16* __restrict__ xinB,
    const _Float16* __restrict__ wF,   const _Float16* __restrict__ wB,
    const float* __restrict__ hbF,     const float* __restrict__ hbB,
    _Float16* __restrict__ xoutF,      _Float16* __restrict__ xoutB,
    float* __restrict__ outF,          float* __restrict__ outB,
    const int write_out)
{
  const int dir = blockIdx.z;
  const _Float16* xin = dir ? xinB : xinF;
  const _Float16* wgt = dir ? wB   : wF;
  const float*    hb  = dir ? hbB  : hbF;
  _Float16*      xout = dir ? xoutB : xoutF;
  float*         outp = dir ? outB  : outF;

  const int n0 = blockIdx.x << 7;
  const int m0 = blockIdx.y << 7;

  __shared__ char smem[49152];
  char* smA = smem;
  char* smN = smem + 16384;
  char* smG = smem + 32768;

  const int tid  = threadIdx.x;
  const int lane = tid & 63;
  const int wv   = tid >> 6;
  const int wm   = wv >> 1, wn = wv & 1;
  const int r15  = lane & 15, rk = lane >> 4;
  const int swz  = (r15 & 7) << 4;

  f4 an[4][4] = {};
  f4 ag[4][4] = {};

  for (int kt = 0; kt < 8; ++kt) {
    const int kbase = kt << 6;
    __syncthreads();
    #pragma unroll
    for (int i = 0; i < 4; ++i) {
      const int c    = (i << 8) + tid;
      const int row  = c >> 3;
      const int cbs  = ((c & 7) << 4) ^ ((row & 7) << 4);
      const int kof  = kbase + (cbs >> 1);
      const int dsto = (((i << 8) + (tid & 192)) << 4);
      __builtin_amdgcn_global_load_lds(AS1(xin + (((size_t)(m0 + row)) << 9) + kof), AS3(smA + dsto), 16, 0, 0);
      __builtin_amdgcn_global_load_lds(AS1(wgt + (((size_t)(n0 + row)) << 9) + kof), AS3(smN + dsto), 16, 0, 0);
      __builtin_amdgcn_global_load_lds(AS1(wgt + (((size_t)(512 + n0 + row)) << 9) + kof), AS3(smG + dsto), 16, 0, 0);
    }
    asm volatile("s_waitcnt vmcnt(0)" ::: "memory");
    __syncthreads();
    #pragma unroll
    for (int kk = 0; kk < 2; ++kk) {
      h8 av[4], nv[4], gv[4];
      #pragma unroll
      for (int mi = 0; mi < 4; ++mi) {
        const int row = (wm << 6) + (mi << 4) + r15;
        av[mi] = *reinterpret_cast<const h8*>(smA + row * 128 + (((kk << 6) + (rk << 4)) ^ swz));
      }
      #pragma unroll
      for (int ni = 0; ni < 4; ++ni) {
        const int row = (wn << 6) + (ni << 4) + r15;
        const int o = row * 128 + (((kk << 6) + (rk << 4)) ^ swz);
        nv[ni] = *reinterpret_cast<const h8*>(smN + o);
        gv[ni] = *reinterpret_cast<const h8*>(smG + o);
      }
      #pragma unroll
      for (int mi = 0; mi < 4; ++mi)
        #pragma unroll
        for (int ni = 0; ni < 4; ++ni) {
          an[mi][ni] = __builtin_amdgcn_mfma_f32_16x16x32_f16(av[mi], nv[ni], an[mi][ni], 0, 0, 0);
          ag[mi][ni] = __builtin_amdgcn_mfma_f32_16x16x32_f16(av[mi], gv[ni], ag[mi][ni], 0, 0, 0);
        }
    }
  }

  // epilogue: gating; write next-x (fp16) and final fp32 output slice
  #pragma unroll
  for (int ni = 0; ni < 4; ++ni) {
    const int col = n0 + (wn << 6) + (ni << 4) + r15;
    const float bn = hb[col];
    const float bg = hb[512 + col];
    #pragma unroll
    for (int mi = 0; mi < 4; ++mi) {
      const int mr = m0 + (wm << 6) + (mi << 4) + (rk << 2);
      #pragma unroll
      for (int r = 0; r < 4; ++r) {
        const size_t m = (size_t)(mr + r);
        const float xo = (float)xin[(m << 9) + col];
        const float nl = fmaxf(an[mi][ni][r] + bn, 0.f);
        const float gt = ag[mi][ni][r] + bg;
        const float g  = 1.f / (1.f + __expf(-gt));
        const float xn = g * xo + (1.f - g) * nl;
        xout[(m << 9) + col] = (_Float16)xn;
        if (write_out) outp[m * 1024 + col] = xn;
      }
    }
  }
}

// ---------------------------------------------------------------------------
extern "C" void kernel_launch(void* const* d_in, const int* in_sizes, int n_in,
                              void* d_out, int out_size, void* d_ws, size_t ws_size,
                              hipStream_t stream) {
  (void)in_sizes; (void)n_in; (void)out_size; (void)ws_size;
  const float* inputs   = (const float*)d_in[0];
  const float* fwd_pad  = (const float*)d_in[1];
  const float* bwd_pad  = (const float*)d_in[2];
  const float* fwd_w    = (const float*)d_in[3];
  const float* fwd_b    = (const float*)d_in[4];
  const float* bwd_w    = (const float*)d_in[5];
  const float* bwd_b    = (const float*)d_in[6];
  const float* fwd_hw_w = (const float*)d_in[7];
  const float* fwd_hw_b = (const float*)d_in[8];
  const float* bwd_hw_w = (const float*)d_in[9];
  const float* bwd_hw_b = (const float*)d_in[10];
  float* out = (float*)d_out;

  // workspace layout (fp16), total ~97 MiB
  _Float16* ws = (_Float16*)d_ws;
  size_t off = 0;
  auto alloc = [&](size_t n) { _Float16* p = ws + off; off += n; return p; };
  const size_t MH = (size_t)16384 * 512;   // 8,388,608
  _Float16* in_h = alloc(MH);
  _Float16* xAf  = alloc(MH);
  _Float16* xBf  = alloc(MH);
  _Float16* xAb  = alloc(MH);
  _Float16* xBb  = alloc(MH);
  _Float16* cwF  = alloc((size_t)2 * 512 * 2048);   // conv w fwd, both layers
  _Float16* cwB  = alloc((size_t)2 * 512 * 2048);
  _Float16* hwF  = alloc((size_t)2 * 2 * 1024 * 512);
  _Float16* hwB  = alloc((size_t)2 * 2 * 1024 * 512);
  _Float16* pF   = alloc(2 * 3 * 512);
  _Float16* pB   = alloc(2 * 3 * 512);

  auto cvt = [&](const float* s, _Float16* d, int n) {
    cvt_kernel<<<dim3(n >> 10), dim3(256), 0, stream>>>(s, d, n);
  };
  cvt(inputs,   in_h, 1 << 23);
  cvt(fwd_w,    cwF,  1 << 21);
  cvt(bwd_w,    cwB,  1 << 21);
  cvt(fwd_hw_w, hwF,  1 << 21);
  cvt(bwd_hw_w, hwB,  1 << 21);
  cvt(fwd_pad,  pF,   3072);
  cvt(bwd_pad,  pB,   3072);

  _Float16* curF = in_h;
  _Float16* curB = in_h;
  _Float16* pingF = xAf; _Float16* pongF = xBf;
  _Float16* pingB = xAb; _Float16* pongB = xBb;

  for (int l = 0; l < 2; ++l) {
    conv_kernel<<<dim3(4, 128, 2), dim3(256), 0, stream>>>(
        curF, curB,
        cwF + (size_t)l * 512 * 2048, cwB + (size_t)l * 512 * 2048,
        fwd_b + l * 512, bwd_b + l * 512,
        pF + l * 1536, pB + l * 1536,
        pingF, pingB);
    for (int j = 0; j < 2; ++j) {
      const _Float16* hinF = (j == 0) ? pingF : pongF;
      const _Float16* hinB = (j == 0) ? pingB : pongB;
      _Float16* houtF = (j == 0) ? pongF : pingF;
      _Float16* houtB = (j == 0) ? pongB : pingB;
      hw_kernel<<<dim3(4, 128, 2), dim3(256), 0, stream>>>(
          hinF, hinB,
          hwF + (size_t)(l * 2 + j) * 1024 * 512, hwB + (size_t)(l * 2 + j) * 1024 * 512,
          fwd_hw_b + (l * 2 + j) * 1024, bwd_hw_b + (l * 2 + j) * 1024,
          houtF, houtB,
          out + (size_t)l * 16384 * 1024, out + (size_t)l * 16384 * 1024 + 512,
          (j == 1) ? 1 : 0);
    }
    curF = pingF; curB = pingB;
    _Float16* t;
    t = pingF; pingF = pongF; pongF = t;
    t = pingB; pingB = pongB; pongB = t;
  }
}

// Round 4
// 615.058 us; speedup vs baseline: 1.0105x; 1.0105x over previous
//
#include <hip/hip_runtime.h>

// ---------------------------------------------------------------------------
// Bengio03HighwayBiLm: L=2 layers of {windowed conv GEMM + 2 highway steps},
// fwd+bwd directions. fp16 MFMA (16x16x32), fp32 accum.
// B=32 S=512 H=512 W=3 IN=2048 NHW=2
// Round 4 (= round 3 resubmit after infra failure): 256x256 tiles, 8 waves,
// dbuf LDS + counted vmcnt(8) pipeline, XCD-chunked block swizzle, conv
// K-order permutation for L2 window reuse.
// ---------------------------------------------------------------------------

typedef __attribute__((ext_vector_type(8))) _Float16 h8;
typedef __attribute__((ext_vector_type(4))) float f4;

#define AS1(p) ((__attribute__((address_space(1))) void*)(p))
#define AS3(p) ((__attribute__((address_space(3))) void*)(p))

// ---- fp32 -> fp16 conversion (vector x4) ----------------------------------
__global__ void cvt_kernel(const float* __restrict__ in, _Float16* __restrict__ out, int n) {
  int i = (blockIdx.x * blockDim.x + threadIdx.x) * 4;
  if (i >= n) return;
  float4 v = *reinterpret_cast<const float4*>(in + i);
  union { _Float16 h[4]; unsigned long long u; } p;
  p.h[0] = (_Float16)v.x; p.h[1] = (_Float16)v.y;
  p.h[2] = (_Float16)v.z; p.h[3] = (_Float16)v.w;
  *reinterpret_cast<unsigned long long*>(out + i) = p.u;
}

// ---------------------------------------------------------------------------
// Conv GEMM: C[m,h] = relu( sum_{k<2048} win[m,k] * W[h,k] + bias[h] )
// win[m=b*512+s, k] = padded[b, (s + tof)*512 + k], tof = dir?3:0
// padded rows t: t<3 -> fwd_pad[t], 3<=t<515 -> x[t-3], t>=515 -> bwd_pad[t-515]
// BM=BN=256, BK=64, 8 waves (2M x 4N), wave out 128x64 (acc[8][4] f32x4).
// LDS: A dbuf 2x32KB + B dbuf 2x32KB = 128 KB. XOR swizzle ((row&7)<<4) on
// SOURCE col at staging (global_load_lds writes linearly) and on ds_read.
// Pipeline per K-tile: B2 barrier -> STAGE(next, 8 loads) -> vmcnt(8) -> B1
// barrier -> COMPUTE(cur).  Loads stay in flight across the whole compute.
// K-order: kt = (t&3)*8 + (t>>2)  (window-offset-major -> L2 reuse of x-slabs)
// ---------------------------------------------------------------------------
__global__ __launch_bounds__(512, 2) void conv_kernel(
    const _Float16* __restrict__ xinF, const _Float16* __restrict__ xinB,
    const _Float16* __restrict__ wF,   const _Float16* __restrict__ wB,
    const float* __restrict__ biasF,   const float* __restrict__ biasB,
    const _Float16* __restrict__ padF, const _Float16* __restrict__ padB,
    _Float16* __restrict__ xoutF,      _Float16* __restrict__ xoutB)
{
  // XCD-chunked swizzle over 256 blocks: paired n-blocks (same A m-panel)
  // get consecutive swz -> same XCD chunk.
  const int bid = blockIdx.x;
  const int swzb = ((bid & 7) << 5) + (bid >> 3);
  const int nblk = swzb & 1;
  const int mblk = (swzb >> 1) & 63;
  const int dir  = swzb >> 7;

  const _Float16* xin  = dir ? xinB  : xinF;
  const _Float16* wgt  = dir ? wB    : wF;
  const float*    bias = dir ? biasB : biasF;
  _Float16*       xout = dir ? xoutB : xoutF;
  const int tof = dir ? 3 : 0;

  const int n0 = nblk << 8;
  const int m0 = mblk << 8;
  const int b  = m0 >> 9;
  const int s0 = m0 & 511;

  __shared__ char smem[131072];
  char* A0 = smem;
  char* A1 = smem + 32768;
  char* Bu0 = smem + 65536;
  char* Bu1 = smem + 98304;

  const int tid  = threadIdx.x;
  const int lane = tid & 63;
  const int wv   = tid >> 6;
  const int wm   = wv >> 2, wn = wv & 3;          // 2M x 4N
  const int r15  = lane & 15, rk = lane >> 4;
  const int swzk = (r15 & 7) << 4;

  f4 acc[8][4] = {};

  auto STAGE = [&](char* sA, char* sB, int t) {
    const int kt = ((t & 3) << 3) | (t >> 2);     // window-offset-major order
    const int kbase = kt << 6;
    #pragma unroll
    for (int i = 0; i < 4; ++i) {
      const int c   = (i << 9) + tid;             // chunk 0..2047
      const int row = c >> 3;                     // 0..255
      const int cbs = ((c & 7) << 4) ^ ((row & 7) << 4);
      const int kg  = kbase + (cbs >> 1);
      const int tr  = s0 + row + tof + (kg >> 9);
      const int hh  = kg & 511;
      const _Float16* src;
      if (tr < 3)        src = padF + tr * 512 + hh;
      else if (tr < 515) src = xin + ((((size_t)(b << 9)) + (tr - 3)) << 9) + hh;
      else               src = padB + (tr - 515) * 512 + hh;
      char* dst = sA + (((i << 9) + (tid & 448)) << 4);
      __builtin_amdgcn_global_load_lds(AS1(src), AS3(dst), 16, 0, 0);
    }
    #pragma unroll
    for (int i = 0; i < 4; ++i) {
      const int c   = (i << 9) + tid;
      const int row = c >> 3;
      const int cbs = ((c & 7) << 4) ^ ((row & 7) << 4);
      const _Float16* src = wgt + (((size_t)(n0 + row)) << 11) + kbase + (cbs >> 1);
      char* dst = sB + (((i << 9) + (tid & 448)) << 4);
      __builtin_amdgcn_global_load_lds(AS1(src), AS3(dst), 16, 0, 0);
    }
  };

  auto COMPUTE = [&](char* sA, char* sB) {
    #pragma unroll
    for (int kk = 0; kk < 2; ++kk) {
      h8 av[8], bv[4];
      #pragma unroll
      for (int mi = 0; mi < 8; ++mi) {
        const int row = (wm << 7) + (mi << 4) + r15;
        av[mi] = *reinterpret_cast<const h8*>(sA + row * 128 + (((kk << 6) + (rk << 4)) ^ swzk));
      }
      #pragma unroll
      for (int ni = 0; ni < 4; ++ni) {
        const int row = (wn << 6) + (ni << 4) + r15;
        bv[ni] = *reinterpret_cast<const h8*>(sB + row * 128 + (((kk << 6) + (rk << 4)) ^ swzk));
      }
      __builtin_amdgcn_s_setprio(1);
      #pragma unroll
      for (int mi = 0; mi < 8; ++mi)
        #pragma unroll
        for (int ni = 0; ni < 4; ++ni)
          acc[mi][ni] = __builtin_amdgcn_mfma_f32_16x16x32_f16(av[mi], bv[ni], acc[mi][ni], 0, 0, 0);
      __builtin_amdgcn_s_setprio(0);
    }
  };

  STAGE(A0, Bu0, 0);
  for (int t = 0; t < 31; ++t) {
    char* cA = (t & 1) ? A1 : A0;
    char* cB = (t & 1) ? Bu1 : Bu0;
    char* nA = (t & 1) ? A0 : A1;
    char* nB = (t & 1) ? Bu0 : Bu1;
    __builtin_amdgcn_s_barrier();                     // B2: prev readers done
    STAGE(nA, nB, t + 1);                             // 8+ loads in flight
    asm volatile("s_waitcnt vmcnt(8)" ::: "memory");  // tile-t loads landed
    __builtin_amdgcn_s_barrier();                     // B1: all waves' t landed
    asm volatile("" ::: "memory");
    COMPUTE(cA, cB);
  }
  asm volatile("s_waitcnt vmcnt(0)" ::: "memory");
  __builtin_amdgcn_s_barrier();
  asm volatile("" ::: "memory");
  COMPUTE(A1, Bu1);

  // epilogue: +bias, relu, store fp16
  #pragma unroll
  for (int ni = 0; ni < 4; ++ni) {
    const int col = n0 + (wn << 6) + (ni << 4) + r15;
    const float bb = bias[col];
    #pragma unroll
    for (int mi = 0; mi < 8; ++mi) {
      const int mr = m0 + (wm << 7) + (mi << 4) + (rk << 2);
      #pragma unroll
      for (int r = 0; r < 4; ++r) {
        float v = acc[mi][ni][r] + bb;
        v = fmaxf(v, 0.f);
        xout[(((size_t)(mr + r)) << 9) + col] = (_Float16)v;
      }
    }
  }
}

// ---------------------------------------------------------------------------
// Highway step: proj[m,g] = sum_h x[m,h]*hw_w[g,h]+hw_b[g], g in [0,1024)
// x_new = sig(proj[512+h])*x + (1-sig)*relu(proj[h])
// BM=256, 128 output cols per block (nonlin rows n0.. + gate rows 512+n0..
// stacked into one 256-row B tile). 8 waves (4M x 2N), wave out 64x64 with
// DUAL accumulators (nonlin + gate) so the gating epilogue stays in-register.
// Same dbuf + counted-vmcnt pipeline, nt = 8 K-tiles.
// ---------------------------------------------------------------------------
__global__ __launch_bounds__(512, 2) void hw_kernel(
    const _Float16* __restrict__ xinF, const _Float16* __restrict__ xinB,
    const _Float16* __restrict__ wF,   const _Float16* __restrict__ wB,
    const float* __restrict__ hbF,     const float* __restrict__ hbB,
    _Float16* __restrict__ xoutF,      _Float16* __restrict__ xoutB,
    float* __restrict__ outF,          float* __restrict__ outB,
    const int write_out)
{
  // XCD-chunked swizzle over 512 blocks: the 4 n-blocks sharing an A m-panel
  // get consecutive swz -> same XCD chunk.
  const int bid = blockIdx.x;
  const int swzb = ((bid & 7) << 6) + (bid >> 3);
  const int nblk = swzb & 3;
  const int mblk = (swzb >> 2) & 63;
  const int dir  = swzb >> 8;

  const _Float16* xin = dir ? xinB : xinF;
  const _Float16* wgt = dir ? wB   : wF;
  const float*    hb  = dir ? hbB  : hbF;
  _Float16*      xout = dir ? xoutB : xoutF;
  float*         outp = dir ? outB  : outF;

  const int n0 = nblk << 7;      // 128-col output group
  const int m0 = mblk << 8;

  __shared__ char smem[131072];
  char* A0 = smem;
  char* A1 = smem + 32768;
  char* Bu0 = smem + 65536;
  char* Bu1 = smem + 98304;

  const int tid  = threadIdx.x;
  const int lane = tid & 63;
  const int wv   = tid >> 6;
  const int wm   = wv >> 1, wn = wv & 1;          // 4M x 2N
  const int r15  = lane & 15, rk = lane >> 4;
  const int swzk = (r15 & 7) << 4;

  f4 an[4][4] = {};
  f4 ag[4][4] = {};

  auto STAGE = [&](char* sA, char* sB, int t) {
    const int kbase = t << 6;
    #pragma unroll
    for (int i = 0; i < 4; ++i) {
      const int c   = (i << 9) + tid;
      const int row = c >> 3;
      const int cbs = ((c & 7) << 4) ^ ((row & 7) << 4);
      const int kof = kbase + (cbs >> 1);
      char* dstA = sA + (((i << 9) + (tid & 448)) << 4);
      __builtin_amdgcn_global_load_lds(AS1(xin + (((size_t)(m0 + row)) << 9) + kof),
                                       AS3(dstA), 16, 0, 0);
      // B rows: r<128 -> nonlin weight row n0+r ; r>=128 -> gate row 512+n0+(r-128)
      const int grow = n0 + (row & 127) + ((row >> 7) << 9);
      char* dstB = sB + (((i << 9) + (tid & 448)) << 4);
      __builtin_amdgcn_global_load_lds(AS1(wgt + (((size_t)grow) << 9) + kof),
                                       AS3(dstB), 16, 0, 0);
    }
  };

  auto COMPUTE = [&](char* sA, char* sB) {
    #pragma unroll
    for (int kk = 0; kk < 2; ++kk) {
      h8 av[4], nv[4], gv[4];
      #pragma unroll
      for (int mi = 0; mi < 4; ++mi) {
        const int row = (wm << 6) + (mi << 4) + r15;
        av[mi] = *reinterpret_cast<const h8*>(sA + row * 128 + (((kk << 6) + (rk << 4)) ^ swzk));
      }
      #pragma unroll
      for (int ni = 0; ni < 4; ++ni) {
        const int rowN = (wn << 6) + (ni << 4) + r15;
        const int cb = (((kk << 6) + (rk << 4)) ^ swzk);
        nv[ni] = *reinterpret_cast<const h8*>(sB + rowN * 128 + cb);
        gv[ni] = *reinterpret_cast<const h8*>(sB + (128 + rowN) * 128 + cb);
      }
      __builtin_amdgcn_s_setprio(1);
      #pragma unroll
      for (int mi = 0; mi < 4; ++mi)
        #pragma unroll
        for (int ni = 0; ni < 4; ++ni) {
          an[mi][ni] = __builtin_amdgcn_mfma_f32_16x16x32_f16(av[mi], nv[ni], an[mi][ni], 0, 0, 0);
          ag[mi][ni] = __builtin_amdgcn_mfma_f32_16x16x32_f16(av[mi], gv[ni], ag[mi][ni], 0, 0, 0);
        }
      __builtin_amdgcn_s_setprio(0);
    }
  };

  STAGE(A0, Bu0, 0);
  for (int t = 0; t < 7; ++t) {
    char* cA = (t & 1) ? A1 : A0;
    char* cB = (t & 1) ? Bu1 : Bu0;
    char* nA = (t & 1) ? A0 : A1;
    char* nB = (t & 1) ? Bu0 : Bu1;
    __builtin_amdgcn_s_barrier();
    STAGE(nA, nB, t + 1);
    asm volatile("s_waitcnt vmcnt(8)" ::: "memory");
    __builtin_amdgcn_s_barrier();
    asm volatile("" ::: "memory");
    COMPUTE(cA, cB);
  }
  asm volatile("s_waitcnt vmcnt(0)" ::: "memory");
  __builtin_amdgcn_s_barrier();
  asm volatile("" ::: "memory");
  COMPUTE(A1, Bu1);

  // epilogue: gating; write next-x (fp16) and final fp32 output slice
  #pragma unroll
  for (int ni = 0; ni < 4; ++ni) {
    const int col = n0 + (wn << 6) + (ni << 4) + r15;
    const float bn = hb[col];
    const float bg = hb[512 + col];
    #pragma unroll
    for (int mi = 0; mi < 4; ++mi) {
      const int mr = m0 + (wm << 6) + (mi << 4) + (rk << 2);
      #pragma unroll
      for (int r = 0; r < 4; ++r) {
        const size_t m = (size_t)(mr + r);
        const float xo = (float)xin[(m << 9) + col];
        const float nl = fmaxf(an[mi][ni][r] + bn, 0.f);
        const float gt = ag[mi][ni][r] + bg;
        const float g  = 1.f / (1.f + __expf(-gt));
        const float xn = g * xo + (1.f - g) * nl;
        xout[(m << 9) + col] = (_Float16)xn;
        if (write_out) outp[m * 1024 + col] = xn;
      }
    }
  }
}

// ---------------------------------------------------------------------------
extern "C" void kernel_launch(void* const* d_in, const int* in_sizes, int n_in,
                              void* d_out, int out_size, void* d_ws, size_t ws_size,
                              hipStream_t stream) {
  (void)in_sizes; (void)n_in; (void)out_size; (void)ws_size;
  const float* inputs   = (const float*)d_in[0];
  const float* fwd_pad  = (const float*)d_in[1];
  const float* bwd_pad  = (const float*)d_in[2];
  const float* fwd_w    = (const float*)d_in[3];
  const float* fwd_b    = (const float*)d_in[4];
  const float* bwd_w    = (const float*)d_in[5];
  const float* bwd_b    = (const float*)d_in[6];
  const float* fwd_hw_w = (const float*)d_in[7];
  const float* fwd_hw_b = (const float*)d_in[8];
  const float* bwd_hw_w = (const float*)d_in[9];
  const float* bwd_hw_b = (const float*)d_in[10];
  float* out = (float*)d_out;

  // workspace layout (fp16), total ~97 MiB
  _Float16* ws = (_Float16*)d_ws;
  size_t off = 0;
  auto alloc = [&](size_t n) { _Float16* p = ws + off; off += n; return p; };
  const size_t MH = (size_t)16384 * 512;   // 8,388,608
  _Float16* in_h = alloc(MH);
  _Float16* xAf  = alloc(MH);
  _Float16* xBf  = alloc(MH);
  _Float16* xAb  = alloc(MH);
  _Float16* xBb  = alloc(MH);
  _Float16* cwF  = alloc((size_t)2 * 512 * 2048);
  _Float16* cwB  = alloc((size_t)2 * 512 * 2048);
  _Float16* hwF  = alloc((size_t)2 * 2 * 1024 * 512);
  _Float16* hwB  = alloc((size_t)2 * 2 * 1024 * 512);
  _Float16* pF   = alloc(2 * 3 * 512);
  _Float16* pB   = alloc(2 * 3 * 512);

  auto cvt = [&](const float* s, _Float16* d, int n) {
    cvt_kernel<<<dim3(n >> 10), dim3(256), 0, stream>>>(s, d, n);
  };
  cvt(inputs,   in_h, 1 << 23);
  cvt(fwd_w,    cwF,  1 << 21);
  cvt(bwd_w,    cwB,  1 << 21);
  cvt(fwd_hw_w, hwF,  1 << 21);
  cvt(bwd_hw_w, hwB,  1 << 21);
  cvt(fwd_pad,  pF,   3072);
  cvt(bwd_pad,  pB,   3072);

  _Float16* curF = in_h;
  _Float16* curB = in_h;
  _Float16* pingF = xAf; _Float16* pongF = xBf;
  _Float16* pingB = xAb; _Float16* pongB = xBb;

  for (int l = 0; l < 2; ++l) {
    conv_kernel<<<dim3(256), dim3(512), 0, stream>>>(
        curF, curB,
        cwF + (size_t)l * 512 * 2048, cwB + (size_t)l * 512 * 2048,
        fwd_b + l * 512, bwd_b + l * 512,
        pF + l * 1536, pB + l * 1536,
        pingF, pingB);
    for (int j = 0; j < 2; ++j) {
      const _Float16* hinF = (j == 0) ? pingF : pongF;
      const _Float16* hinB = (j == 0) ? pingB : pongB;
      _Float16* houtF = (j == 0) ? pongF : pingF;
      _Float16* houtB = (j == 0) ? pongB : pingB;
      hw_kernel<<<dim3(512), dim3(512), 0, stream>>>(
          hinF, hinB,
          hwF + (size_t)(l * 2 + j) * 1024 * 512, hwB + (size_t)(l * 2 + j) * 1024 * 512,
          fwd_hw_b + (l * 2 + j) * 1024, bwd_hw_b + (l * 2 + j) * 1024,
          houtF, houtB,
          out + (size_t)l * 16384 * 1024, out + (size_t)l * 16384 * 1024 + 512,
          (j == 1) ? 1 : 0);
    }
    curF = pingF; curB = pingB;
    _Float16* t;
    t = pingF; pingF = pongF; pongF = t;
    t = pingB; pingB = pongB; pongB = t;
  }
}

// Round 6
// 609.837 us; speedup vs baseline: 1.0192x; 1.0086x over previous
//
#include <hip/hip_runtime.h>

// ---------------------------------------------------------------------------
// Bengio03HighwayBiLm: L=2 layers of {windowed conv GEMM + 2 highway steps},
// fwd+bwd directions. fp16 MFMA (16x16x32), fp32 accum.
// B=32 S=512 H=512 W=3 IN=2048 NHW=2
// Round 6 (= round 5 resubmit after infra failure): conv/cvt UNCHANGED from
// round 4 (controlled A/B). hw rebuilt: BM=128 x 512 B-rows (256 nonlin +
// 256 gate), BK=64, 160 KiB LDS dbuf, uniform 10 loads/wave/tile, counted
// vmcnt(10) pipeline, 1-pass x streaming.
// ---------------------------------------------------------------------------

typedef __attribute__((ext_vector_type(8))) _Float16 h8;
typedef __attribute__((ext_vector_type(4))) float f4;

#define AS1(p) ((__attribute__((address_space(1))) void*)(p))
#define AS3(p) ((__attribute__((address_space(3))) void*)(p))

// ---- fp32 -> fp16 conversion (vector x4) ----------------------------------
__global__ void cvt_kernel(const float* __restrict__ in, _Float16* __restrict__ out, int n) {
  int i = (blockIdx.x * blockDim.x + threadIdx.x) * 4;
  if (i >= n) return;
  float4 v = *reinterpret_cast<const float4*>(in + i);
  union { _Float16 h[4]; unsigned long long u; } p;
  p.h[0] = (_Float16)v.x; p.h[1] = (_Float16)v.y;
  p.h[2] = (_Float16)v.z; p.h[3] = (_Float16)v.w;
  *reinterpret_cast<unsigned long long*>(out + i) = p.u;
}

// ---------------------------------------------------------------------------
// Conv GEMM (unchanged from round 4): BM=BN=256, BK=64, 8 waves (2Mx4N),
// dbuf 128 KB LDS, counted vmcnt(8), window-offset-major K order, XCD swizzle.
// ---------------------------------------------------------------------------
__global__ __launch_bounds__(512, 2) void conv_kernel(
    const _Float16* __restrict__ xinF, const _Float16* __restrict__ xinB,
    const _Float16* __restrict__ wF,   const _Float16* __restrict__ wB,
    const float* __restrict__ biasF,   const float* __restrict__ biasB,
    const _Float16* __restrict__ padF, const _Float16* __restrict__ padB,
    _Float16* __restrict__ xoutF,      _Float16* __restrict__ xoutB)
{
  const int bid = blockIdx.x;
  const int swzb = ((bid & 7) << 5) + (bid >> 3);
  const int nblk = swzb & 1;
  const int mblk = (swzb >> 1) & 63;
  const int dir  = swzb >> 7;

  const _Float16* xin  = dir ? xinB  : xinF;
  const _Float16* wgt  = dir ? wB    : wF;
  const float*    bias = dir ? biasB : biasF;
  _Float16*       xout = dir ? xoutB : xoutF;
  const int tof = dir ? 3 : 0;

  const int n0 = nblk << 8;
  const int m0 = mblk << 8;
  const int b  = m0 >> 9;
  const int s0 = m0 & 511;

  __shared__ char smem[131072];
  char* A0 = smem;
  char* A1 = smem + 32768;
  char* Bu0 = smem + 65536;
  char* Bu1 = smem + 98304;

  const int tid  = threadIdx.x;
  const int lane = tid & 63;
  const int wv   = tid >> 6;
  const int wm   = wv >> 2, wn = wv & 3;          // 2M x 4N
  const int r15  = lane & 15, rk = lane >> 4;
  const int swzk = (r15 & 7) << 4;

  f4 acc[8][4] = {};

  auto STAGE = [&](char* sA, char* sB, int t) {
    const int kt = ((t & 3) << 3) | (t >> 2);     // window-offset-major order
    const int kbase = kt << 6;
    #pragma unroll
    for (int i = 0; i < 4; ++i) {
      const int c   = (i << 9) + tid;             // chunk 0..2047
      const int row = c >> 3;                     // 0..255
      const int cbs = ((c & 7) << 4) ^ ((row & 7) << 4);
      const int kg  = kbase + (cbs >> 1);
      const int tr  = s0 + row + tof + (kg >> 9);
      const int hh  = kg & 511;
      const _Float16* src;
      if (tr < 3)        src = padF + tr * 512 + hh;
      else if (tr < 515) src = xin + ((((size_t)(b << 9)) + (tr - 3)) << 9) + hh;
      else               src = padB + (tr - 515) * 512 + hh;
      char* dst = sA + (((i << 9) + (tid & 448)) << 4);
      __builtin_amdgcn_global_load_lds(AS1(src), AS3(dst), 16, 0, 0);
    }
    #pragma unroll
    for (int i = 0; i < 4; ++i) {
      const int c   = (i << 9) + tid;
      const int row = c >> 3;
      const int cbs = ((c & 7) << 4) ^ ((row & 7) << 4);
      const _Float16* src = wgt + (((size_t)(n0 + row)) << 11) + kbase + (cbs >> 1);
      char* dst = sB + (((i << 9) + (tid & 448)) << 4);
      __builtin_amdgcn_global_load_lds(AS1(src), AS3(dst), 16, 0, 0);
    }
  };

  auto COMPUTE = [&](char* sA, char* sB) {
    #pragma unroll
    for (int kk = 0; kk < 2; ++kk) {
      h8 av[8], bv[4];
      #pragma unroll
      for (int mi = 0; mi < 8; ++mi) {
        const int row = (wm << 7) + (mi << 4) + r15;
        av[mi] = *reinterpret_cast<const h8*>(sA + row * 128 + (((kk << 6) + (rk << 4)) ^ swzk));
      }
      #pragma unroll
      for (int ni = 0; ni < 4; ++ni) {
        const int row = (wn << 6) + (ni << 4) + r15;
        bv[ni] = *reinterpret_cast<const h8*>(sB + row * 128 + (((kk << 6) + (rk << 4)) ^ swzk));
      }
      __builtin_amdgcn_s_setprio(1);
      #pragma unroll
      for (int mi = 0; mi < 8; ++mi)
        #pragma unroll
        for (int ni = 0; ni < 4; ++ni)
          acc[mi][ni] = __builtin_amdgcn_mfma_f32_16x16x32_f16(av[mi], bv[ni], acc[mi][ni], 0, 0, 0);
      __builtin_amdgcn_s_setprio(0);
    }
  };

  STAGE(A0, Bu0, 0);
  for (int t = 0; t < 31; ++t) {
    char* cA = (t & 1) ? A1 : A0;
    char* cB = (t & 1) ? Bu1 : Bu0;
    char* nA = (t & 1) ? A0 : A1;
    char* nB = (t & 1) ? Bu0 : Bu1;
    __builtin_amdgcn_s_barrier();                     // B2: prev readers done
    STAGE(nA, nB, t + 1);                             // 8+ loads in flight
    asm volatile("s_waitcnt vmcnt(8)" ::: "memory");  // tile-t loads landed
    __builtin_amdgcn_s_barrier();                     // B1: all waves' t landed
    asm volatile("" ::: "memory");
    COMPUTE(cA, cB);
  }
  asm volatile("s_waitcnt vmcnt(0)" ::: "memory");
  __builtin_amdgcn_s_barrier();
  asm volatile("" ::: "memory");
  COMPUTE(A1, Bu1);

  // epilogue: +bias, relu, store fp16
  #pragma unroll
  for (int ni = 0; ni < 4; ++ni) {
    const int col = n0 + (wn << 6) + (ni << 4) + r15;
    const float bb = bias[col];
    #pragma unroll
    for (int mi = 0; mi < 8; ++mi) {
      const int mr = m0 + (wm << 7) + (mi << 4) + (rk << 2);
      #pragma unroll
      for (int r = 0; r < 4; ++r) {
        float v = acc[mi][ni][r] + bb;
        v = fmaxf(v, 0.f);
        xout[(((size_t)(mr + r)) << 9) + col] = (_Float16)v;
      }
    }
  }
}

// ---------------------------------------------------------------------------
// Highway step v2: proj[m,g] = sum_h x[m,h]*hw_w[g,h]+hw_b[g], g in [0,1024)
// x_new = sig(proj[512+h])*x + (1-sig)*relu(proj[h])
// BM=128 m-rows, B-tile = 512 weight rows (nonlin n0..n0+255 + gate
// 512+n0..+255), BK=64, 8 K-tiles. 8 waves (2M x 4N): wave = 64m x
// {64 nonlin + 64 gate} cols, dual acc an/ag (128 VGPR).
// LDS: A dbuf 2x16KB + B dbuf 2x64KB = 160 KiB (full pool), 1 block/CU.
// Staging: 10 uniform global_load_lds instr/wave/tile -> counted vmcnt(10).
// Grid 512 = 2dir x 128mblk x 2nblk, XCD-chunked (nblk pair shares x in L2).
// ---------------------------------------------------------------------------
__global__ __launch_bounds__(512, 2) void hw_kernel(
    const _Float16* __restrict__ xinF, const _Float16* __restrict__ xinB,
    const _Float16* __restrict__ wF,   const _Float16* __restrict__ wB,
    const float* __restrict__ hbF,     const float* __restrict__ hbB,
    _Float16* __restrict__ xoutF,      _Float16* __restrict__ xoutB,
    float* __restrict__ outF,          float* __restrict__ outB,
    const int write_out)
{
  const int bid = blockIdx.x;
  const int swzb = ((bid & 7) << 6) + (bid >> 3);   // bijective over 512
  const int nblk = swzb & 1;
  const int mblk = (swzb >> 1) & 127;
  const int dir  = swzb >> 8;

  const _Float16* xin = dir ? xinB : xinF;
  const _Float16* wgt = dir ? wB   : wF;
  const float*    hb  = dir ? hbB  : hbF;
  _Float16*      xout = dir ? xoutB : xoutF;
  float*         outp = dir ? outB  : outF;

  const int n0 = nblk << 8;      // output-col group base (256 cols)
  const int m0 = mblk << 7;      // 128 m-rows

  __shared__ char smem[163840];
  char* A0  = smem;              // 16 KB
  char* A1  = smem + 16384;
  char* Bu0 = smem + 32768;      // 64 KB (rows 0..255 nonlin, 256..511 gate)
  char* Bu1 = smem + 98304;

  const int tid  = threadIdx.x;
  const int lane = tid & 63;
  const int wv   = tid >> 6;
  const int wm   = wv >> 2, wn = wv & 3;          // 2M x 4N
  const int r15  = lane & 15, rk = lane >> 4;
  const int swzk = (r15 & 7) << 4;

  f4 an[4][4] = {};
  f4 ag[4][4] = {};

  auto STAGE = [&](char* sA, char* sB, int t) {
    const int kbase = t << 6;
    #pragma unroll
    for (int i = 0; i < 2; ++i) {                 // A: 1024 chunks (16 KB)
      const int ca  = (i << 9) + tid;
      const int row = ca >> 3;                    // 0..127
      const int col = ((ca & 7) << 4) ^ ((row & 7) << 4);
      const _Float16* src = xin + (((size_t)(m0 + row)) << 9) + kbase + (col >> 1);
      char* dst = sA + (((i << 9) + (tid & 448)) << 4);
      __builtin_amdgcn_global_load_lds(AS1(src), AS3(dst), 16, 0, 0);
    }
    #pragma unroll
    for (int i = 0; i < 8; ++i) {                 // B: 4096 chunks (64 KB)
      const int cb  = (i << 9) + tid;
      const int row = cb >> 3;                    // 0..511
      const int col = ((cb & 7) << 4) ^ ((row & 7) << 4);
      const int grow = n0 + (row & 255) + ((row >> 8) << 9);  // nonlin | gate
      const _Float16* src = wgt + (((size_t)grow) << 9) + kbase + (col >> 1);
      char* dst = sB + (((i << 9) + (tid & 448)) << 4);
      __builtin_amdgcn_global_load_lds(AS1(src), AS3(dst), 16, 0, 0);
    }
  };

  auto COMPUTE = [&](char* sA, char* sB) {
    #pragma unroll
    for (int kk = 0; kk < 2; ++kk) {
      h8 av[4], nv[4], gv[4];
      #pragma unroll
      for (int mi = 0; mi < 4; ++mi) {
        const int row = (wm << 6) + (mi << 4) + r15;
        av[mi] = *reinterpret_cast<const h8*>(sA + row * 128 + (((kk << 6) + (rk << 4)) ^ swzk));
      }
      #pragma unroll
      for (int ni = 0; ni < 4; ++ni) {
        const int rowN = (wn << 6) + (ni << 4) + r15;
        const int cb2 = (((kk << 6) + (rk << 4)) ^ swzk);
        nv[ni] = *reinterpret_cast<const h8*>(sB + rowN * 128 + cb2);
        gv[ni] = *reinterpret_cast<const h8*>(sB + (256 + rowN) * 128 + cb2);
      }
      __builtin_amdgcn_s_setprio(1);
      #pragma unroll
      for (int mi = 0; mi < 4; ++mi)
        #pragma unroll
        for (int ni = 0; ni < 4; ++ni) {
          an[mi][ni] = __builtin_amdgcn_mfma_f32_16x16x32_f16(av[mi], nv[ni], an[mi][ni], 0, 0, 0);
          ag[mi][ni] = __builtin_amdgcn_mfma_f32_16x16x32_f16(av[mi], gv[ni], ag[mi][ni], 0, 0, 0);
        }
      __builtin_amdgcn_s_setprio(0);
    }
  };

  STAGE(A0, Bu0, 0);
  for (int t = 0; t < 7; ++t) {
    char* cA = (t & 1) ? A1 : A0;
    char* cB = (t & 1) ? Bu1 : Bu0;
    char* nA = (t & 1) ? A0 : A1;
    char* nB = (t & 1) ? Bu0 : Bu1;
    __builtin_amdgcn_s_barrier();                     // B2: prev readers done
    STAGE(nA, nB, t + 1);                             // 10 loads/wave in flight
    asm volatile("s_waitcnt vmcnt(10)" ::: "memory"); // tile-t loads landed
    __builtin_amdgcn_s_barrier();                     // B1
    asm volatile("" ::: "memory");
    COMPUTE(cA, cB);
  }
  asm volatile("s_waitcnt vmcnt(0)" ::: "memory");
  __builtin_amdgcn_s_barrier();
  asm volatile("" ::: "memory");
  COMPUTE(A1, Bu1);

  // epilogue: gating; write next-x (fp16) and final fp32 output slice
  #pragma unroll
  for (int ni = 0; ni < 4; ++ni) {
    const int col = n0 + (wn << 6) + (ni << 4) + r15;
    const float bn = hb[col];
    const float bg = hb[512 + col];
    #pragma unroll
    for (int mi = 0; mi < 4; ++mi) {
      const int mr = m0 + (wm << 6) + (mi << 4) + (rk << 2);
      #pragma unroll
      for (int r = 0; r < 4; ++r) {
        const size_t m = (size_t)(mr + r);
        const float xo = (float)xin[(m << 9) + col];
        const float nl = fmaxf(an[mi][ni][r] + bn, 0.f);
        const float gt = ag[mi][ni][r] + bg;
        const float g  = 1.f / (1.f + __expf(-gt));
        const float xn = g * xo + (1.f - g) * nl;
        xout[(m << 9) + col] = (_Float16)xn;
        if (write_out) outp[m * 1024 + col] = xn;
      }
    }
  }
}

// ---------------------------------------------------------------------------
extern "C" void kernel_launch(void* const* d_in, const int* in_sizes, int n_in,
                              void* d_out, int out_size, void* d_ws, size_t ws_size,
                              hipStream_t stream) {
  (void)in_sizes; (void)n_in; (void)out_size; (void)ws_size;
  const float* inputs   = (const float*)d_in[0];
  const float* fwd_pad  = (const float*)d_in[1];
  const float* bwd_pad  = (const float*)d_in[2];
  const float* fwd_w    = (const float*)d_in[3];
  const float* fwd_b    = (const float*)d_in[4];
  const float* bwd_w    = (const float*)d_in[5];
  const float* bwd_b    = (const float*)d_in[6];
  const float* fwd_hw_w = (const float*)d_in[7];
  const float* fwd_hw_b = (const float*)d_in[8];
  const float* bwd_hw_w = (const float*)d_in[9];
  const float* bwd_hw_b = (const float*)d_in[10];
  float* out = (float*)d_out;

  // workspace layout (fp16), total ~97 MiB
  _Float16* ws = (_Float16*)d_ws;
  size_t off = 0;
  auto alloc = [&](size_t n) { _Float16* p = ws + off; off += n; return p; };
  const size_t MH = (size_t)16384 * 512;   // 8,388,608
  _Float16* in_h = alloc(MH);
  _Float16* xAf  = alloc(MH);
  _Float16* xBf  = alloc(MH);
  _Float16* xAb  = alloc(MH);
  _Float16* xBb  = alloc(MH);
  _Float16* cwF  = alloc((size_t)2 * 512 * 2048);
  _Float16* cwB  = alloc((size_t)2 * 512 * 2048);
  _Float16* hwF  = alloc((size_t)2 * 2 * 1024 * 512);
  _Float16* hwB  = alloc((size_t)2 * 2 * 1024 * 512);
  _Float16* pF   = alloc(2 * 3 * 512);
  _Float16* pB   = alloc(2 * 3 * 512);

  auto cvt = [&](const float* s, _Float16* d, int n) {
    cvt_kernel<<<dim3(n >> 10), dim3(256), 0, stream>>>(s, d, n);
  };
  cvt(inputs,   in_h, 1 << 23);
  cvt(fwd_w,    cwF,  1 << 21);
  cvt(bwd_w,    cwB,  1 << 21);
  cvt(fwd_hw_w, hwF,  1 << 21);
  cvt(bwd_hw_w, hwB,  1 << 21);
  cvt(fwd_pad,  pF,   3072);
  cvt(bwd_pad,  pB,   3072);

  _Float16* curF = in_h;
  _Float16* curB = in_h;
  _Float16* pingF = xAf; _Float16* pongF = xBf;
  _Float16* pingB = xAb; _Float16* pongB = xBb;

  for (int l = 0; l < 2; ++l) {
    conv_kernel<<<dim3(256), dim3(512), 0, stream>>>(
        curF, curB,
        cwF + (size_t)l * 512 * 2048, cwB + (size_t)l * 512 * 2048,
        fwd_b + l * 512, bwd_b + l * 512,
        pF + l * 1536, pB + l * 1536,
        pingF, pingB);
    for (int j = 0; j < 2; ++j) {
      const _Float16* hinF = (j == 0) ? pingF : pongF;
      const _Float16* hinB = (j == 0) ? pingB : pongB;
      _Float16* houtF = (j == 0) ? pongF : pingF;
      _Float16* houtB = (j == 0) ? pongB : pingB;
      hw_kernel<<<dim3(512), dim3(512), 0, stream>>>(
          hinF, hinB,
          hwF + (size_t)(l * 2 + j) * 1024 * 512, hwB + (size_t)(l * 2 + j) * 1024 * 512,
          fwd_hw_b + (l * 2 + j) * 1024, bwd_hw_b + (l * 2 + j) * 1024,
          houtF, houtB,
          out + (size_t)l * 16384 * 1024, out + (size_t)l * 16384 * 1024 + 512,
          (j == 1) ? 1 : 0);
    }
    curF = pingF; curB = pingB;
    _Float16* t;
    t = pingF; pingF = pongF; pongF = t;
    t = pingB; pingB = pongB; pongB = t;
  }
}